// Round 8
// baseline (130.458 us; speedup 1.0000x reference)
//
#include <hip/hip_runtime.h>

// MoE: out[b,:] = sum_e softmax(gate(x))[b,e] * (W3_e^T @ relu(W2_e^T @ relu(W1_e^T @ x_b + b1) + b2) + b3)
// Tokens-as-N MFMA. L1 uses 16x16x16 f16 (K=7 useful, k=4q+j). L2/L3/gate-L2 use 16x16x32 f16
// with K-permutation pi(q*8+j)=q*4+(j&3)+16*(j>>2) so C/D layout == next layer's B layout
// in-lane (HW-verified across R2-R15: absmax 0.0156).
// R16: R15 (3 waves/SIMD, LDS weight images, b2-as-f32-C-init, TB=2) + EXPERT-LOOP SOFTWARE
//      PIPELINE. R15 accounting: ~6.5k cyc/tile/wave vs ~500 cyc of static issue -- no pipe
//      saturated (VALU 47, MFMA 31, DS ~24, HBM 5) => latency-bound. Prime suspect: each
//      expert stage opens with 3-5 ds_reads (~120+ cyc latency) consumed immediately by the
//      MFMA chain; 8 stages/iter expose ~1-2k cyc/wave. Fix: rolling double-buffer -- issue
//      expert e+1's loads (w1/w2lo/w2hi/b2clo/b2chi) before expert e's compute; expert 0's
//      loads hoisted above the gate chains. +12-14 transient regs: ~80-82 <= 85 cap, still
//      3 waves/SIMD, zero spills (falsifiable: WRITE_SIZE must stay 8.19 MB, VGPR <= 85).

typedef _Float16 half2_t __attribute__((ext_vector_type(2)));
typedef _Float16 half4_t __attribute__((ext_vector_type(4)));
typedef _Float16 half8_t __attribute__((ext_vector_type(8)));
typedef __fp16   fp16v2  __attribute__((ext_vector_type(2)));
typedef float  float4_t __attribute__((ext_vector_type(4)));
typedef float  float2_t __attribute__((ext_vector_type(2)));
typedef int    int2_t   __attribute__((ext_vector_type(2)));
typedef int    int4_t   __attribute__((ext_vector_type(4)));

#define MFMA_K32(A, B, C) __builtin_amdgcn_mfma_f32_16x16x32_f16((A), (B), (C), 0, 0, 0)
#define MFMA_K16(A, B, C) __builtin_amdgcn_mfma_f32_16x16x16f16((A), (B), (C), 0, 0, 0)

static constexpr int E_ = 8, DIN_ = 6, H_ = 32, TB_ = 2;   // tiles per iteration

union H8U { half2_t h2[4]; half8_t h8; int4_t i4; };
union H4U { half2_t h2[2]; half4_t h4; int2_t i2; };
union W1U { H4U f[2]; int4_t i4; };    // 16B: both L1 A-fragments (or both gate-L1 frags)
union HI  { half2_t h; int i; };
union PKU { fp16v2 p; half2_t h; };

__device__ __forceinline__ half2_t pkrtz(float a, float b) {
    PKU u; u.p = __builtin_amdgcn_cvt_pkrtz(a, b);
    return u.h;
}

__device__ __forceinline__ half2_t relu2(half2_t v) {
    const half2_t z = {(_Float16)0.0f, (_Float16)0.0f};
    return __builtin_elementwise_max(v, z);
}

// full gate chain for one tile: logits (log2 domain) -> ex weights for this lane's expert
// pair {2q,2q+1} + deferred-normalization reciprocal (valid in quads 0-1)
__device__ __forceinline__ void gate_eval(
    half4_t xB, const H4U* G1, const H8U& G2, float4_t bg2F, float4_t zero4,
    int gsrc, int q, float& ga, float& gb, float& rs)
{
    float4_t hgLo = MFMA_K16(G1[0].h4, xB, zero4);
    float4_t hgHi = MFMA_K16(G1[1].h4, xB, zero4);
    H8U uh;
    uh.h2[0] = relu2(pkrtz(hgLo[0], hgLo[1]));
    uh.h2[1] = relu2(pkrtz(hgLo[2], hgLo[3]));
    uh.h2[2] = relu2(pkrtz(hgHi[0], hgHi[1]));
    uh.h2[3] = relu2(pkrtz(hgHi[2], hgHi[3]));
    float4_t gl = MFMA_K32(G2.h8, uh.h8, bg2F);
    float ex0 = __builtin_amdgcn_exp2f(gl[0]);
    float ex1 = __builtin_amdgcn_exp2f(gl[1]);
    float ex2 = __builtin_amdgcn_exp2f(gl[2]);
    float ex3 = __builtin_amdgcn_exp2f(gl[3]);
    float s = (ex0 + ex1) + (ex2 + ex3);
    s += __shfl_xor(s, 16);
    rs = __builtin_amdgcn_rcpf(s);
    HI pa, pb;
    pa.h = pkrtz(ex0, ex1);
    pb.h = pkrtz(ex2, ex3);
    int va = __builtin_amdgcn_ds_bpermute(gsrc, pa.i);
    int vb = __builtin_amdgcn_ds_bpermute(gsrc, pb.i);
    HI gsel; gsel.i = (q & 1) ? vb : va;   // lane(q,t): ex[t,2q], ex[t,2q+1]
    ga = (float)gsel.h[0];
    gb = (float)gsel.h[1];
}

__global__ __launch_bounds__(256)
__attribute__((amdgpu_waves_per_eu(3, 3)))
void moe_kernel(
    const float* __restrict__ x,  const float* __restrict__ W1, const float* __restrict__ b1,
    const float* __restrict__ W2, const float* __restrict__ b2, const float* __restrict__ W3,
    const float* __restrict__ b3, const float* __restrict__ Wg1, const float* __restrict__ bg1,
    const float* __restrict__ Wg2, const float* __restrict__ bg2,
    float* __restrict__ out, int nTiles, int tilesPerWave)
{
    const int tid  = threadIdx.x;
    const int lane = tid & 63;
    const int t    = lane & 15;   // token slot
    const int q    = lane >> 4;   // K-quad / row-quad
    const int wv   = tid >> 6;    // wave in block
    const int gw   = (blockIdx.x << 2) + wv;   // global wave id (waves independent in loop)
    const int eo   = t >> 1;      // the ONE expert whose L3 rows this lane holds

    // block-uniform images (every wave reads the same fragments)
    __shared__ W1U  w1img[E_][64];        //  8 KB: [e][lane] -> both L1 A-fragments
    __shared__ H8U  w2img[E_][2][64];     // 16 KB: [e][half][lane] -> L2 A-fragment
    __shared__ float b2f32[E_][H_];       //  1 KB: b2 rows (f32 C-init, broadcast reads)
    __shared__ W1U  g1img[64];            //  1 KB: per-lane gate-L1 fragments
    __shared__ H8U  g2img[64];            //  1 KB: per-lane gate-L2 fragment
    __shared__ H8U  w3img[64];            //  1 KB: per-lane sparse W3 fragment (expert eo)

    const float L2E = 1.44269504f;

    // ---- build expert images: wave wv packs experts {2wv, 2wv+1} (pi layout as R2-R15)
    #pragma unroll
    for (int j = 0; j < 2; ++j) {
        const int e = wv * 2 + j;
        W1U w1v;
        #pragma unroll
        for (int f = 0; f < 2; ++f) {
            float v0 = 0.f, v1 = 0.f, v2 = 0.f, v3 = 0.f;
            const float* We = W1 + (size_t)e * DIN_ * H_ + f * 16 + t;
            if (q == 0)      { v0 = We[0 * H_]; v1 = We[1 * H_]; v2 = We[2 * H_]; v3 = We[3 * H_]; }
            else if (q == 1) { v0 = We[4 * H_]; v1 = We[5 * H_]; v2 = b1[e * H_ + f * 16 + t]; }
            w1v.f[f].h2[0] = pkrtz(v0, v1); w1v.f[f].h2[1] = pkrtz(v2, v3);
        }
        w1img[e][lane] = w1v;
        H8U w2lo, w2hi;
        #pragma unroll
        for (int p = 0; p < 4; ++p) {
            int c0 = ((p >> 1) << 4) + q * 4 + ((p & 1) << 1);
            w2lo.h2[p] = pkrtz(W2[(e * H_ + c0) * H_ + 0  + t], W2[(e * H_ + c0 + 1) * H_ + 0  + t]);
            w2hi.h2[p] = pkrtz(W2[(e * H_ + c0) * H_ + 16 + t], W2[(e * H_ + c0 + 1) * H_ + 16 + t]);
        }
        w2img[e][0][lane] = w2lo;
        w2img[e][1][lane] = w2hi;
        if (lane < H_) b2f32[e][lane] = b2[e * H_ + lane];   // f32 C-init rows
    }

    // ---- wave 0 builds the per-lane gate + W3 images (lane-determined, identical all waves)
    if (wv == 0) {
        W1U g1v;
        #pragma unroll
        for (int f = 0; f < 2; ++f) {
            float v0 = 0.f, v1 = 0.f, v2 = 0.f, v3 = 0.f;
            if (q == 0) {
                v0 = Wg1[0 * H_ + f * 16 + t]; v1 = Wg1[1 * H_ + f * 16 + t];
                v2 = Wg1[2 * H_ + f * 16 + t]; v3 = Wg1[3 * H_ + f * 16 + t];
            } else if (q == 1) {
                v0 = Wg1[4 * H_ + f * 16 + t]; v1 = Wg1[5 * H_ + f * 16 + t];
                v2 = bg1[f * 16 + t];          v3 = 0.f;
            }
            g1v.f[f].h2[0] = pkrtz(v0, v1); g1v.f[f].h2[1] = pkrtz(v2, v3);
        }
        g1img[lane] = g1v;
        H8U g2v, w3v;
        #pragma unroll
        for (int p = 0; p < 4; ++p) {
            int c0 = ((p >> 1) << 4) + q * 4 + ((p & 1) << 1);
            float v0 = (t < E_) ? Wg2[c0 * E_ + t] * L2E : 0.f;
            float v1 = (t < E_) ? Wg2[(c0 + 1) * E_ + t] * L2E : 0.f;
            g2v.h2[p] = pkrtz(v0, v1);
            w3v.h2[p] = pkrtz(W3[(eo * H_ + c0) * 2 + (t & 1)],
                              W3[(eo * H_ + c0 + 1) * 2 + (t & 1)]);
        }
        g2img[lane] = g2v;
        w3img[lane] = w3v;
    }

    // ---- persistent C-inits: bg2 (log2 domain), b3 for all 16 Y rows m=(e,o)
    float4_t bg2F, b3F;
    #pragma unroll
    for (int r = 0; r < 4; ++r) {
        int m = q * 4 + r;
        bg2F[r] = (m < E_) ? bg2[m] * L2E : 0.f;
        b3F[r]  = b3[m];
    }
    const float4_t zero4 = {0.f, 0.f, 0.f, 0.f};
    const int4_t  zeroi  = {0, 0, 0, 0};

    // gate pull: lane(q,t) fetches ex[t,2q],ex[t,2q+1] from lane (q>>1)*16+t
    const int gsrc = ((((q >> 1) << 4) | t) << 2);

    __syncthreads();   // images ready; NO barriers inside the loop

    const int tile0 = gw * tilesPerWave;

    // ---- per-lane x source: quad0 reads x[t][0..3]; quads>=1 read x[t][4..5]
    const int xo1 = (q == 0) ? 0 : 4;
    const int xo2 = (q == 0) ? 2 : 4;
    const float* xq = x + ((size_t)tile0 * 16 + t) * DIN_;
    float2_t la[TB_], lb[TB_];
    #pragma unroll
    for (int u = 0; u < TB_; ++u) {
        la[u] = float2_t{0.f, 0.f};
        lb[u] = float2_t{0.f, 0.f};
        if (tile0 + u < nTiles) {
            la[u] = *(const float2_t*)(xq + (size_t)u * 16 * DIN_ + xo1);
            lb[u] = *(const float2_t*)(xq + (size_t)u * 16 * DIN_ + xo2);
        }
    }

    HI onei; onei.h = pkrtz(1.f, 0.f);
    const bool isq0 = (q == 0);

    // ---- main loop: two tiles per iteration, expert loop software-pipelined
    for (int it = 0; it < tilesPerWave; it += TB_) {
        const int tb = tile0 + it;
        if (tb >= nTiles) break;            // uniform per wave

        // re-read per-lane images each iteration (volatile: must NOT be hoisted to
        // persistent registers -- that would blow the 3-wave arch budget)
        W1U g1v; g1v.i4 = *(const volatile int4_t*)&g1img[lane].i4;
        H8U g2v; g2v.i4 = *(const volatile int4_t*)&g2img[lane].i4;
        H8U w3v; w3v.i4 = *(const volatile int4_t*)&w3img[lane].i4;

        // ---- expert 0's loads issued HERE: their ~120+ cyc LDS latency hides under the
        //      x-pack + two gate chains below (the R16 pipeline prologue)
        W1U w1c  = w1img[0][lane];
        H8U w2loC = w2img[0][0][lane];
        H8U w2hiC = w2img[0][1][lane];
        float4_t b2loC = *(const float4_t*)&b2f32[0][q * 4];
        float4_t b2hiC = *(const float4_t*)&b2f32[0][16 + q * 4];

        // x B-fragments (K=16): q0:(x0..x3) q1:(x4,x5,1,dc) q2/q3: dc (A=0 there)
        H4U ux[TB_];
        #pragma unroll
        for (int u = 0; u < TB_; ++u) {
            ux[u].h2[0] = pkrtz(la[u][0], la[u][1]);
            HI hb; hb.h = pkrtz(lb[u][0], lb[u][1]);
            HI se; se.i = isq0 ? hb.i : onei.i;
            ux[u].h2[1] = se.h;
        }

        // prefetch next pair's x
        if (it + TB_ < tilesPerWave) {
            const float* xn = xq + (size_t)(it + TB_) * 16 * DIN_;
            #pragma unroll
            for (int u = 0; u < TB_; ++u) {
                if (tb + TB_ + u < nTiles) {
                    la[u] = *(const float2_t*)(xn + (size_t)u * 16 * DIN_ + xo1);
                    lb[u] = *(const float2_t*)(xn + (size_t)u * 16 * DIN_ + xo2);
                }
            }
        }

        // gates (once per tile; two independent chains; cover expert-0 load latency)
        float ga[TB_], gb[TB_], rs[TB_];
        #pragma unroll
        for (int u = 0; u < TB_; ++u)
            gate_eval(ux[u].h4, g1v.f, g2v, bg2F, zero4, gsrc, q, ga[u], gb[u], rs[u]);

        // all 8 experts x 2 tiles, SOFTWARE-PIPELINED: expert e+1's five LDS loads issue
        // before expert e's MFMA chain consumes its (already-arrived) fragments
        float4_t Ya[TB_], Yb[TB_];
        #pragma unroll
        for (int u = 0; u < TB_; ++u) { Ya[u] = b3F; Yb[u] = zero4; }
        #pragma unroll
        for (int e = 0; e < E_; ++e) {
            W1U w1n; H8U w2loN, w2hiN; float4_t b2loN, b2hiN;
            if (e + 1 < E_) {
                w1n   = w1img[e + 1][lane];
                w2loN = w2img[e + 1][0][lane];
                w2hiN = w2img[e + 1][1][lane];
                b2loN = *(const float4_t*)&b2f32[e + 1][q * 4];
                b2hiN = *(const float4_t*)&b2f32[e + 1][16 + q * 4];
            }
            H8U a3;  a3.i4 = (eo == e) ? w3v.i4 : zeroi;   // sparse L3 rows: mask per expert

            #pragma unroll
            for (int u = 0; u < TB_; ++u) {
                float4_t lo = MFMA_K16(w1c.f[0].h4, ux[u].h4, zero4);
                float4_t hi = MFMA_K16(w1c.f[1].h4, ux[u].h4, zero4);
                H8U u1;
                u1.h2[0] = relu2(pkrtz(lo[0], lo[1]));
                u1.h2[1] = relu2(pkrtz(lo[2], lo[3]));
                u1.h2[2] = relu2(pkrtz(hi[0], hi[1]));
                u1.h2[3] = relu2(pkrtz(hi[2], hi[3]));
                float4_t lo2 = MFMA_K32(w2loC.h8, u1.h8, b2loC);   // bias in f32 C-init
                float4_t hi2 = MFMA_K32(w2hiC.h8, u1.h8, b2hiC);
                H8U u2;
                u2.h2[0] = relu2(pkrtz(lo2[0], lo2[1]));
                u2.h2[1] = relu2(pkrtz(lo2[2], lo2[3]));
                u2.h2[2] = relu2(pkrtz(hi2[0], hi2[1]));
                u2.h2[3] = relu2(pkrtz(hi2[2], hi2[3]));
                if (e & 1) Yb[u] = MFMA_K32(a3.h8, u2.h8, Yb[u]);
                else       Ya[u] = MFMA_K32(a3.h8, u2.h8, Ya[u]);
            }

            if (e + 1 < E_) {       // rotate the pipeline buffers (dead copies after unroll)
                w1c = w1n; w2loC = w2loN; w2hiC = w2hiN; b2loC = b2loN; b2hiC = b2hiN;
            }
        }

        // epilogues: lane(q,t) holds Y rows m=4q+r -> experts {2q,2q+1}, o=r&1
        #pragma unroll
        for (int u = 0; u < TB_; ++u) {
            const int tile = tb + u;
            float p0 = ga[u] * (Ya[u][0] + Yb[u][0]) + gb[u] * (Ya[u][2] + Yb[u][2]);
            float p1 = ga[u] * (Ya[u][1] + Yb[u][1]) + gb[u] * (Ya[u][3] + Yb[u][3]);
            p0 += __shfl_xor(p0, 16);
            p0 += __shfl_xor(p0, 32);
            p1 += __shfl_xor(p1, 16);
            p1 += __shfl_xor(p1, 32);
            if (tile < nTiles && lane < 16) {
                float2_t o = {p0 * rs[u], p1 * rs[u]};
                *(float2_t*)(out + ((size_t)tile * 16 + t) * 2) = o;
            }
        }
    }
}

extern "C" void kernel_launch(void* const* d_in, const int* in_sizes, int n_in,
                              void* d_out, int out_size, void* d_ws, size_t ws_size,
                              hipStream_t stream) {
    const float* x   = (const float*)d_in[0];
    const float* W1  = (const float*)d_in[1];
    const float* b1  = (const float*)d_in[2];
    const float* W2  = (const float*)d_in[3];
    const float* b2  = (const float*)d_in[4];
    const float* W3  = (const float*)d_in[5];
    const float* b3  = (const float*)d_in[6];
    const float* Wg1 = (const float*)d_in[7];
    const float* bg1 = (const float*)d_in[8];
    const float* Wg2 = (const float*)d_in[9];
    const float* bg2 = (const float*)d_in[10];
    float* out = (float*)d_out;

    const int B      = in_sizes[0] / DIN_;
    const int nTiles = (B + 15) / 16;
    // waves_per_eu(3,3): arch cap ~85; demand ~80-82 with the pipeline buffers -> no spills.
    // 768 blocks x 4 waves = 3072 waves = exact 3 blocks/CU (12 waves/CU), 84 KB LDS/CU.
    // tpw = ceil(65536/3072) = 22; ragged tail handled by per-tile guards.
    const int blocks = 768;
    const int wavesTotal = blocks * 4;
    const int tpw = (nTiles + wavesTotal - 1) / wavesTotal;

    moe_kernel<<<blocks, 256, 0, stream>>>(x, W1, b1, W2, b2, W3, b3,
                                           Wg1, bg1, Wg2, bg2, out, nTiles, tpw);
}